// Round 9
// baseline (163.433 us; speedup 1.0000x reference)
//
#include <hip/hip_runtime.h>
#include <math.h>

#define NBINS 257
#define NMEL 80
#define MEL_FLOOR 1.192092955078125e-07f

constexpr int B = 16;
constexpr int T = 480000;
constexpr int F = 1 + (T - 400) / 160;   // 2998
constexpr int MT = 64;                    // frames per block
constexpr int BPB = (F + MT - 1) / MT;    // 47 blocks per batch
constexpr int AP = 424;                   // A LDS pitch (f16)
constexpr int PP = 265;                   // P LDS pitch (f32)

// ws float offsets
#define WS_BH    0         // f16[13][32][64][8] hi = 212992 f16 = 106496 floats
#define WS_BL    106496    // f16 lo, same size
#define WS_K0    212992    // int[80]
#define WS_LEN   213072    // int[80]
#define WS_WGT   213152    // float[32*80]
#define WS_PART  215712    // float[16*47][2][80] = 120320
#define WS_STAT  336032    // float[16][2][80]

typedef _Float16 f16x8 __attribute__((ext_vector_type(8)));
typedef float f32x4 __attribute__((ext_vector_type(4)));

// ---------------- Setup A: mel tables ----------------
__global__ __launch_bounds__(256) void setup_mel_kernel(
    const float* __restrict__ fil, float* __restrict__ ws)
{
    const int t = threadIdx.x;
    __shared__ int sh_k0[3][NMEL], sh_k1[3][NMEL];
    __shared__ int sh_K0[NMEL], sh_LEN[NMEL];
    if (t < 240) {
        int m = t % NMEL, r = t / NMEL;
        int kb = r * 86, ke = (kb + 86 < NBINS) ? (kb + 86) : NBINS;
        int k0 = -1, k1 = -1;
        for (int k = kb; k < ke; ++k) {
            if (fil[k * NMEL + m] > 0.0f) { if (k0 < 0) k0 = k; k1 = k; }
        }
        sh_k0[r][m] = k0; sh_k1[r][m] = k1;
    }
    __syncthreads();
    if (t < NMEL) {
        int k0 = -1, k1 = -1;
        for (int r = 0; r < 3; ++r) {
            int a = sh_k0[r][t], b1 = sh_k1[r][t];
            if (a >= 0) { if (k0 < 0) k0 = a; k1 = b1; }
        }
        int len = (k0 < 0) ? 0 : (k1 - k0 + 1);
        if (len > 32) len = 32;
        if (k0 < 0) k0 = 0;
        ((int*)ws)[WS_K0 + t] = k0;
        ((int*)ws)[WS_LEN + t] = len;
        sh_K0[t] = k0; sh_LEN[t] = len;
    }
    __syncthreads();
    for (int idx = t; idx < 32 * NMEL; idx += 256) {
        int j = idx / NMEL, m = idx - j * NMEL;
        ws[WS_WGT + idx] = (j < sh_LEN[m]) ? fil[(sh_K0[m] + j) * NMEL + m] : 0.0f;
    }
}

// ---------------- Setup B: frag-major split-f16 DFT tables ----------------
// Bpk[ks][n16][lane][j] = D[k][n]; k = ks*32 + (lane>>4)*8 + j,
// n = n16*16 + (lane&15); n = 2*bin + (0:cos, 1:sin); zero for k >= 400.
__global__ __launch_bounds__(64) void setup_dft_kernel(float* __restrict__ ws)
{
    const int blk = blockIdx.x;          // 0..415 = ks*32 + n16
    const int l = threadIdx.x;
    const int n = (blk & 31) * 16 + (l & 15);
    const int bin = n >> 1;
    const int kbase = (blk >> 5) * 32 + (l >> 4) * 8;
    f16x8 vh, vl;
    #pragma unroll
    for (int j = 0; j < 8; ++j) {
        int k = kbase + j;
        float val = 0.0f;
        if (k < 400) {
            int kb = (k * bin) & 511;    // exact mod-512 reduction
            float ang = 6.283185307179586f * (float)kb * (1.0f / 512.0f);
            float s, c;
            sincosf(ang, &s, &c);
            val = (n & 1) ? s : c;
        }
        _Float16 h = (_Float16)val;
        float r = val - (float)h;
        vh[j] = h;
        vl[j] = (_Float16)r;
    }
    ((f16x8*)(ws + WS_BH))[blk * 64 + l] = vh;
    ((f16x8*)(ws + WS_BL))[blk * 64 + l] = vl;
}

// ---------------- Main: 64 frames -> log-mel via split-f16 MFMA ----------------
__global__ __launch_bounds__(512) void gemm_logmel_kernel(
    const float* __restrict__ wav,
    const float* __restrict__ win,
    float* __restrict__ ws,
    float* __restrict__ mel_out)
{
    __shared__ __attribute__((aligned(16))) char lds[155008];
    _Float16* A_hi = (_Float16*)lds;                  // [64][424] f16, 54272 B
    _Float16* A_lo = (_Float16*)(lds + 54272);        // [64][424] f16, 54272 B
    float* P_s    = (float*)lds;                      // [64][265] f32, aliases A (after barrier)
    float* raw    = (float*)(lds + 108544);           // 10496 f32
    float* win_s  = (float*)(lds + 150528);           // 400
    float* S16_s  = (float*)(lds + 152128);           // 656
    float* mean_s = (float*)(lds + 154752);           // 64

    const int t = threadIdx.x;
    const int l = t & 63, w = t >> 6;
    const int bid = blockIdx.x;
    const int b = bid / BPB, blk = bid - b * BPB;
    const int f0 = blk * MT;
    const int nfr = (F - f0 < MT) ? (F - f0) : MT;
    const size_t s0 = (size_t)b * T + (size_t)f0 * 160;

    if (t < 400) win_s[t] = win[t];

    // ---- phase 1a: raw span -> LDS ----
    {
        const float4* src4 = (const float4*)(wav + s0);
        #pragma unroll
        for (int it = 0; it < 6; ++it) {
            int i4 = t + it * 512;
            if (i4 < 2624) {
                float4 v = make_float4(0.f, 0.f, 0.f, 0.f);
                if (s0 + 4 * (size_t)i4 + 3 < (size_t)B * T) v = src4[i4];
                ((float4*)raw)[i4] = v;
            }
        }
    }
    __syncthreads();

    // ---- phase 1b: 16-wide chunk sums -> per-frame means ----
    for (int c = t; c < 656; c += 512) {
        float s = 0.0f;
        #pragma unroll
        for (int q = 0; q < 4; ++q) {
            float4 v = ((const float4*)raw)[4 * c + q];
            s += v.x + v.y + v.z + v.w;
        }
        S16_s[c] = s;
    }
    __syncthreads();
    if (t < MT) {
        float s = 0.0f;
        #pragma unroll
        for (int i = 0; i < 25; ++i) s += S16_s[10 * t + i];
        mean_s[t] = s * (1.0f / 400.0f);
    }
    __syncthreads();

    // ---- phase 1c: build A hi/lo (preemph + window, split f16) ----
    {
        const int f = t >> 3, j = t & 7;
        const float m = mean_s[f];
        const int base = f * 160;
        const bool dead = (f >= nfr);
        int k = j * 52;
        float xm = (k == 0) ? raw[base] : raw[base + k - 1];
        #pragma unroll
        for (int it = 0; it < 26; ++it) {
            float a0 = 0.0f, a1 = 0.0f;
            if (!dead && k < 400) {
                float x0 = raw[base + k];
                float x1 = raw[base + k + 1];
                a0 = (x0 - 0.97f * xm - 0.03f * m) * win_s[k];
                if (k + 1 < 400)
                    a1 = (x1 - 0.97f * x0 - 0.03f * m) * win_s[k + 1];
                xm = x1;
            }
            _Float16 h0 = (_Float16)a0, h1 = (_Float16)a1;
            float r0 = a0 - (float)h0, r1 = a1 - (float)h1;
            _Float16 e0 = (_Float16)r0, e1 = (_Float16)r1;
            unsigned uh = ((unsigned)*(unsigned short*)&h1 << 16) | *(unsigned short*)&h0;
            unsigned ul = ((unsigned)*(unsigned short*)&e1 << 16) | *(unsigned short*)&e0;
            *(unsigned*)&A_hi[f * AP + k] = uh;
            *(unsigned*)&A_lo[f * AP + k] = ul;
            k += 2;
        }
    }
    __syncthreads();

    // ---- phase 2: K-loop, 3-term compensated MFMA ----
    const int lane15 = l & 15, lhi = l >> 4;
    f32x4 acc[4][4] = {};
    const _Float16* Ah = A_hi + lane15 * AP + lhi * 8;
    const _Float16* Al = A_lo + lane15 * AP + lhi * 8;
    const f16x8* bh = (const f16x8*)(ws + WS_BH);
    const f16x8* bl = (const f16x8*)(ws + WS_BL);
    #pragma unroll
    for (int ks = 0; ks < 13; ++ks) {
        f16x8 afh[4], afl[4];
        #pragma unroll
        for (int mf = 0; mf < 4; ++mf) {
            afh[mf] = *(const f16x8*)(Ah + mf * 16 * AP + ks * 32);
            afl[mf] = *(const f16x8*)(Al + mf * 16 * AP + ks * 32);
        }
        #pragma unroll
        for (int nf = 0; nf < 4; ++nf) {
            int bidx = (ks * 32 + w * 4 + nf) * 64 + l;
            f16x8 bfh = bh[bidx];
            f16x8 bfl = bl[bidx];
            #pragma unroll
            for (int mf = 0; mf < 4; ++mf) {
                acc[mf][nf] = __builtin_amdgcn_mfma_f32_16x16x32_f16(afh[mf], bfh, acc[mf][nf], 0, 0, 0);
                acc[mf][nf] = __builtin_amdgcn_mfma_f32_16x16x32_f16(afh[mf], bfl, acc[mf][nf], 0, 0, 0);
                acc[mf][nf] = __builtin_amdgcn_mfma_f32_16x16x32_f16(afl[mf], bfh, acc[mf][nf], 0, 0, 0);
            }
        }
    }
    __syncthreads();   // all A reads done; P may now overwrite A space

    // ---- phase 3a: power spectrum -> P_s (re/im pair combine via shfl) ----
    #pragma unroll
    for (int mf = 0; mf < 4; ++mf)
        #pragma unroll
        for (int nf = 0; nf < 4; ++nf)
            #pragma unroll
            for (int r = 0; r < 4; ++r) {
                float v = acc[mf][nf][r];
                float p = v * v;
                p += __shfl_xor(p, 1);
                if ((l & 1) == 0) {
                    int bin = (w * 64 + nf * 16 + lane15) >> 1;
                    int fl = mf * 16 + lhi * 4 + r;
                    P_s[fl * PP + bin] = p;
                }
            }
    __syncthreads();

    // ---- phase 3b: sparse mel + log + fused stats partials ----
    {
        const int f = t & 63, g = t >> 6;           // f = lane, 8 groups x 10 mels
        const bool live = (f < nfr);
        const size_t outbase = (size_t)(b * F + f0 + f) * NMEL;
        const float* Pf = &P_s[f * PP];
        float* part = ws + WS_PART;
        #pragma unroll
        for (int i = 0; i < 10; ++i) {
            int mel = g * 10 + i;
            int k0 = ((const int*)ws)[WS_K0 + mel];
            int len = ((const int*)ws)[WS_LEN + mel];
            float a = 0.0f;
            for (int q = 0; q < len; ++q)
                a = fmaf(Pf[k0 + q], ws[WS_WGT + q * NMEL + mel], a);
            a = logf(fmaxf(a * 1073741824.0f, MEL_FLOOR));  // restore 32768^2
            if (live) mel_out[outbase + mel] = a;
            float v = live ? a : 0.0f;
            float v2 = v * v;
            #pragma unroll
            for (int m2 = 32; m2 >= 1; m2 >>= 1) {
                v += __shfl_xor(v, m2);
                v2 += __shfl_xor(v2, m2);
            }
            if (f == 0) {
                part[(bid * 2 + 0) * NMEL + mel] = v;
                part[(bid * 2 + 1) * NMEL + mel] = v2;
            }
        }
    }
}

// ---------------- finalize stats (16 blocks x 80 thr) ----------------
__global__ __launch_bounds__(128) void stats_final_kernel(float* __restrict__ ws)
{
    const int b = blockIdx.x;
    const int m = threadIdx.x;
    if (m >= NMEL) return;
    const float* part = ws + WS_PART;
    double s = 0.0, s2 = 0.0;
    for (int c = 0; c < BPB; ++c) {
        int bid = b * BPB + c;
        s += (double)part[(bid * 2 + 0) * NMEL + m];
        s2 += (double)part[(bid * 2 + 1) * NMEL + m];
    }
    double mean = s / (double)F;
    double var = (s2 - s * s / (double)F) / (double)(F - 1);
    ws[WS_STAT + b * 2 * NMEL + m] = (float)mean;
    ws[WS_STAT + b * 2 * NMEL + NMEL + m] = (float)(1.0 / sqrt(var + 1e-7));
}

// ---------------- normalize (float4) + mask ----------------
__global__ __launch_bounds__(256) void norm_mask_kernel(
    float* __restrict__ out, const float* __restrict__ ws)
{
    const float* stat = ws + WS_STAT;
    const int total4 = (B * F * NMEL) / 4;
    const int stride = gridDim.x * blockDim.x;
    float4* out4 = (float4*)out;
    for (int e4 = blockIdx.x * blockDim.x + threadIdx.x; e4 < total4; e4 += stride) {
        int e = e4 * 4;
        int b = e / (F * NMEL);
        int m = e % NMEL;
        const float* sb = stat + b * 2 * NMEL;
        float4 v = out4[e4];
        v.x = (v.x - sb[m + 0]) * sb[NMEL + m + 0];
        v.y = (v.y - sb[m + 1]) * sb[NMEL + m + 1];
        v.z = (v.z - sb[m + 2]) * sb[NMEL + m + 2];
        v.w = (v.w - sb[m + 3]) * sb[NMEL + m + 3];
        out4[e4] = v;
    }
    const int nmask = B * (F / 2);
    float* mask = out + (size_t)B * F * NMEL;
    for (int e = blockIdx.x * blockDim.x + threadIdx.x; e < nmask; e += stride)
        mask[e] = 1.0f;
}

extern "C" void kernel_launch(void* const* d_in, const int* in_sizes, int n_in,
                              void* d_out, int out_size, void* d_ws, size_t ws_size,
                              hipStream_t stream) {
    const float* wav = (const float*)d_in[0];
    const float* fil = (const float*)d_in[1];
    const float* win = (const float*)d_in[2];
    float* out = (float*)d_out;
    float* ws = (float*)d_ws;

    setup_mel_kernel<<<1, 256, 0, stream>>>(fil, ws);
    setup_dft_kernel<<<416, 64, 0, stream>>>(ws);
    gemm_logmel_kernel<<<B * BPB, 512, 0, stream>>>(wav, win, ws, out);  // 752 blocks
    stats_final_kernel<<<B, 128, 0, stream>>>(ws);
    norm_mask_kernel<<<2048, 256, 0, stream>>>(out, ws);
}